// Round 1
// 236.211 us; speedup vs baseline: 1.3018x; 1.3018x over previous
//
#include <hip/hip_runtime.h>

#define LN_EPS 1e-5f

typedef __attribute__((ext_vector_type(8))) short bf16x8;
typedef __attribute__((ext_vector_type(4))) float f32x4;

// Bucketed CSR build parameters: bucket = 128 consecutive dst nodes.
#define BSH 7
#define BSPAN 128
#define BCAP 4096   // staging capacity per bucket (mean 2048, std ~45 -> 45 sigma margin)
#define BIN_TILE 4096  // edges per bin_k block (16 per thread)

__device__ __forceinline__ unsigned short f2bf(float f) {
    union { float f; unsigned u; } x; x.f = f;
    unsigned r = (x.u + 0x7FFFu + ((x.u >> 16) & 1u)) >> 16;
    return (unsigned short)r;
}
__device__ __forceinline__ float bfbits2f(unsigned hi) {  // hi = bf16 bits already in [31:16]
    union { unsigned u; float f; } x; x.u = hi; return x.f;
}

// ---------- conversions / packing ----------
// X fp32 -> bf16, padded rows zeroed. Block 0 also zeroes the bucket cursors.
__global__ void convx_k(const float* __restrict__ X, unsigned short* __restrict__ Xb,
                        int total, int total_pad) {
    int i = blockIdx.x * blockDim.x + threadIdx.x;
    if (i < total_pad) Xb[i] = (i < total) ? f2bf(X[i]) : (unsigned short)0;
}

// Pack both W1 and W2 into B-fragment-contiguous bf16 layout:
// Wp[(((kc*128 + col)*4 + kb)*8) + j] = W[(kc*32 + kb*8 + j)*128 + col]
// Block 0 additionally zeroes gcur[0..nb).
__global__ void packw_k(const float* __restrict__ W1, const float* __restrict__ W2,
                        unsigned short* __restrict__ Wp1, unsigned short* __restrict__ Wp2,
                        int* __restrict__ gcur, int nb) {
    int idx = blockIdx.x * blockDim.x + threadIdx.x;  // 0..32767
    if (blockIdx.x == 0) {
        for (int i = threadIdx.x; i < nb; i += 256) gcur[i] = 0;
    }
    const float* W = (idx < 16384) ? W1 : W2;
    unsigned short* Wp = (idx < 16384) ? Wp1 : Wp2;
    int t = idx & 16383;
    int k = t >> 7, col = t & 127;
    int kc = k >> 5, kr = k & 31, kb = kr >> 3, j = kr & 7;
    Wp[(((kc * 128 + col) * 4 + kb) * 8) + j] = f2bf(W[k * 128 + col]);
}

// ---------- bucketed CSR build ----------
// Pass 1: counting-bin a tile of BIN_TILE edges into nb buckets via LDS counters;
// reserve a contiguous run per (block,bucket) with ONE global atomic per bucket;
// write packed entries (src | localdst<<17) as contiguous runs into bucket-major staging.
__global__ __launch_bounds__(256) void bin_k(const int* __restrict__ src,
                                             const int* __restrict__ dst,
                                             int* __restrict__ gcur,
                                             unsigned* __restrict__ staging,
                                             int nE, int nb) {
    __shared__ int cnt[512];
    __shared__ int gbase[512];
    int tid = threadIdx.x;
    for (int i = tid; i < nb; i += 256) cnt[i] = 0;
    __syncthreads();
    int e0 = blockIdx.x * BIN_TILE;
    unsigned pk[16];
    int bk[16];
    int rk[16];
#pragma unroll
    for (int i = 0; i < 16; ++i) {
        int e = e0 + i * 256 + tid;
        if (e < nE) {
            int s = src[e];
            int d = dst[e];
            int b = d >> BSH;
            rk[i] = atomicAdd(&cnt[b], 1);
            bk[i] = b;
            pk[i] = (unsigned)s | ((unsigned)(d & (BSPAN - 1)) << 17);
        } else {
            bk[i] = -1;
        }
    }
    __syncthreads();
    for (int i = tid; i < nb; i += 256) gbase[i] = atomicAdd(&gcur[i], cnt[i]);
    __syncthreads();
#pragma unroll
    for (int i = 0; i < 16; ++i) {
        if (bk[i] >= 0)
            staging[(size_t)bk[i] * BCAP + gbase[bk[i]] + rk[i]] = pk[i];
    }
}

// Tiny scan over bucket totals -> bucket base offsets; also writes rowptr[n].
__global__ __launch_bounds__(512) void bscan_k(const int* __restrict__ gcur,
                                               int* __restrict__ bbase,
                                               int* __restrict__ rowptr,
                                               int n, int nb, int nE) {
    __shared__ int s[512];
    int tid = threadIdx.x;
    int v = (tid < nb) ? gcur[tid] : 0;
    s[tid] = v;
    __syncthreads();
    for (int off = 1; off < 512; off <<= 1) {
        int t = (tid >= off) ? s[tid - off] : 0;
        __syncthreads();
        s[tid] += t;
        __syncthreads();
    }
    if (tid < nb) bbase[tid] = s[tid] - v;  // exclusive
    if (tid == nb - 1) { bbase[nb] = s[tid]; rowptr[n] = nE; }
}

// Pass 2: one block per bucket. Per-node counts + 128-wide scan + scatter,
// all in LDS. Produces rowptr, dinv, and the final dst-grouped eidx.
__global__ __launch_bounds__(256) void build_k(const unsigned* __restrict__ staging,
                                               const int* __restrict__ bbase,
                                               int* __restrict__ rowptr,
                                               int* __restrict__ eidx,
                                               float* __restrict__ dinv, int n) {
    __shared__ int cnt[BSPAN];
    __shared__ int off[BSPAN];
    __shared__ int s[BSPAN];
    int b = blockIdx.x;
    int tid = threadIdx.x;
    if (tid < BSPAN) cnt[tid] = 0;
    __syncthreads();
    int base = bbase[b];
    int total = bbase[b + 1] - base;
    const unsigned* stg = staging + (size_t)b * BCAP;
    unsigned ent[16];  // BCAP/256 = 16 max entries per thread; statically indexed
#pragma unroll
    for (int k = 0; k < 16; ++k) {
        int i = tid + k * 256;
        unsigned e = 0xFFFFFFFFu;  // sentinel: valid entries have bits[31:24]==0
        if (i < total) {
            e = stg[i];
            atomicAdd(&cnt[(e >> 17) & (BSPAN - 1)], 1);
        }
        ent[k] = e;
    }
    __syncthreads();
    // exclusive scan of cnt[0..127]
    if (tid < BSPAN) s[tid] = cnt[tid];
    __syncthreads();
    for (int o = 1; o < BSPAN; o <<= 1) {
        int t = (tid < BSPAN && tid >= o) ? s[tid - o] : 0;
        __syncthreads();
        if (tid < BSPAN) s[tid] += t;
        __syncthreads();
    }
    if (tid < BSPAN) {
        int excl = s[tid] - cnt[tid];
        off[tid] = excl;  // becomes the scatter cursor
        int node = b * BSPAN + tid;
        if (node < n) {
            rowptr[node] = base + excl;
            dinv[node] = rsqrtf((float)(cnt[tid] + 1));
        }
    }
    __syncthreads();
#pragma unroll
    for (int k = 0; k < 16; ++k) {
        unsigned e = ent[k];
        if (e != 0xFFFFFFFFu) {
            int ld = (e >> 17) & (BSPAN - 1);
            int p = atomicAdd(&off[ld], 1);
            eidx[base + p] = (int)(e & 0x1FFFFu);
        }
    }
}

// ---------- MFMA GEMM: Y[r,:] = bf16( dinv[r] * (Xb[r,:] @ W) ) ----------
// Block: 256 thr = 4 waves; block tile 64 rows x 128 cols.
// Wave (rgrp = wid&1, cgrp = wid>>1): 32 rows x 64 cols = 2 A-frags x 4 B-frags.
__global__ __launch_bounds__(256) void mfma_gemm_k(const unsigned short* __restrict__ Xb,
                                                   const unsigned short* __restrict__ Wp,
                                                   const float* __restrict__ dinv,
                                                   unsigned short* __restrict__ Y, int n) {
    int wid = threadIdx.x >> 6;
    int lane = threadIdx.x & 63;
    int rgrp = wid & 1;
    int cgrp = wid >> 1;
    int row0 = blockIdx.x * 64 + rgrp * 32;
    int m = lane & 15;
    int kb = lane >> 4;  // 0..3

    f32x4 acc[2][4] = {};
#pragma unroll
    for (int kc = 0; kc < 4; ++kc) {
        bf16x8 a[2], b[4];
#pragma unroll
        for (int rs = 0; rs < 2; ++rs) {
            int r = row0 + rs * 16 + m;
            a[rs] = *(const bf16x8*)(Xb + (size_t)r * 128 + kc * 32 + kb * 8);
        }
#pragma unroll
        for (int cf = 0; cf < 4; ++cf) {
            int col = cgrp * 64 + cf * 16 + m;
            b[cf] = *(const bf16x8*)(Wp + (((kc * 128 + col) * 4 + kb) * 8));
        }
#pragma unroll
        for (int rs = 0; rs < 2; ++rs)
#pragma unroll
            for (int cf = 0; cf < 4; ++cf)
                acc[rs][cf] = __builtin_amdgcn_mfma_f32_16x16x32_bf16(a[rs], b[cf], acc[rs][cf], 0, 0, 0);
    }
    // D layout: row = (lane>>4)*4 + reg, col = lane&15
#pragma unroll
    for (int rs = 0; rs < 2; ++rs) {
        int rbase = row0 + rs * 16 + kb * 4;
#pragma unroll
        for (int r = 0; r < 4; ++r) {
            int row = rbase + r;
            if (row >= n) continue;
            float dv = dinv[row];
#pragma unroll
            for (int cf = 0; cf < 4; ++cf) {
                int col = cgrp * 64 + cf * 16 + m;
                Y[(size_t)row * 128 + col] = f2bf(acc[rs][cf][r] * dv);
            }
        }
    }
}

// ---------- fused gather-aggregate + bias + LN + ReLU ----------
// One wave per node; Hs is bf16 (dinv[src] folded in). Lane holds dims {2*lane, 2*lane+1}.
template <bool OUT_BF16>
__global__ __launch_bounds__(256) void agg_ln_k(const unsigned short* __restrict__ Hs,
                                                const float* __restrict__ dinv,
                                                const int* __restrict__ rowptr,
                                                const int* __restrict__ eidx,
                                                const float* __restrict__ bias,
                                                const float* __restrict__ g,
                                                const float* __restrict__ beta,
                                                void* __restrict__ out, int n) {
    int wave = (blockIdx.x * blockDim.x + threadIdx.x) >> 6;
    int lane = threadIdx.x & 63;
    if (wave >= n) return;
    const unsigned* H4 = (const unsigned*)Hs;  // one uint = 2 bf16
    unsigned v0 = H4[(size_t)wave * 64 + lane];
    float ax = bfbits2f(v0 << 16);
    float ay = bfbits2f(v0 & 0xFFFF0000u);
    int beg = rowptr[wave];
    int end = rowptr[wave + 1];
    int e = beg;
    for (; e + 3 < end; e += 4) {
        int s0 = eidx[e], s1 = eidx[e + 1], s2 = eidx[e + 2], s3 = eidx[e + 3];
        unsigned u0 = H4[(size_t)s0 * 64 + lane];
        unsigned u1 = H4[(size_t)s1 * 64 + lane];
        unsigned u2 = H4[(size_t)s2 * 64 + lane];
        unsigned u3 = H4[(size_t)s3 * 64 + lane];
        ax += bfbits2f(u0 << 16) + bfbits2f(u1 << 16) + bfbits2f(u2 << 16) + bfbits2f(u3 << 16);
        ay += bfbits2f(u0 & 0xFFFF0000u) + bfbits2f(u1 & 0xFFFF0000u) +
              bfbits2f(u2 & 0xFFFF0000u) + bfbits2f(u3 & 0xFFFF0000u);
    }
    for (; e < end; ++e) {
        unsigned u0 = H4[(size_t)eidx[e] * 64 + lane];
        ax += bfbits2f(u0 << 16);
        ay += bfbits2f(u0 & 0xFFFF0000u);
    }
    float dt = dinv[wave];
    float vx = ax * dt + bias[2 * lane];
    float vy = ay * dt + bias[2 * lane + 1];
    float sum = vx + vy;
#pragma unroll
    for (int off = 32; off > 0; off >>= 1) sum += __shfl_down(sum, off);
    sum = __shfl(sum, 0);
    float mu = sum * (1.0f / 128.0f);
    float dx = vx - mu, dy = vy - mu;
    float vs = dx * dx + dy * dy;
#pragma unroll
    for (int off = 32; off > 0; off >>= 1) vs += __shfl_down(vs, off);
    vs = __shfl(vs, 0);
    float rstd = rsqrtf(vs * (1.0f / 128.0f) + LN_EPS);
    float o0 = fmaxf(dx * rstd * g[2 * lane] + beta[2 * lane], 0.0f);
    float o1 = fmaxf(dy * rstd * g[2 * lane + 1] + beta[2 * lane + 1], 0.0f);
    if (OUT_BF16) {
        unsigned pack = (unsigned)f2bf(o0) | ((unsigned)f2bf(o1) << 16);
        ((unsigned*)out)[(size_t)wave * 64 + lane] = pack;
    } else {
        ((float2*)out)[(size_t)wave * 64 + lane] = make_float2(o0, o1);
    }
}

extern "C" void kernel_launch(void* const* d_in, const int* in_sizes, int n_in,
                              void* d_out, int out_size, void* d_ws, size_t ws_size,
                              hipStream_t stream) {
    const float* x   = (const float*)d_in[0];
    const int*   ei  = (const int*)d_in[1];
    const float* W1  = (const float*)d_in[2];
    const float* b1  = (const float*)d_in[3];
    const float* g1  = (const float*)d_in[4];
    const float* be1 = (const float*)d_in[5];
    const float* W2  = (const float*)d_in[6];
    const float* b2  = (const float*)d_in[7];
    const float* g2  = (const float*)d_in[8];
    const float* be2 = (const float*)d_in[9];
    float* out = (float*)d_out;

    int n  = in_sizes[0] / 128;   // 50000
    int nE = in_sizes[1] / 2;     // 800000
    const int* src = ei;
    const int* dst = ei + nE;

    int nb = (n + BSPAN - 1) >> BSH;  // 391 buckets
    int nblk64 = (n + 63) / 64;       // GEMM blocks
    int npad   = nblk64 * 64;         // padded rows for OOB-safe frag loads

    char* p = (char*)d_ws;
    auto carve = [&](size_t bytes) {
        char* r = p;
        p += (bytes + 255) & ~(size_t)255;
        return r;
    };
    float*    dinv    = (float*)carve((size_t)n * 4);
    int*      rowptr  = (int*)carve((size_t)(n + 1) * 4);
    int*      eidx    = (int*)carve((size_t)nE * 4);
    int*      gcur    = (int*)carve((size_t)nb * 4);
    int*      bbase   = (int*)carve((size_t)(nb + 1) * 4);
    unsigned* staging = (unsigned*)carve((size_t)nb * BCAP * 4);
    unsigned short* Wp1 = (unsigned short*)carve(16384 * 2);
    unsigned short* Wp2 = (unsigned short*)carve(16384 * 2);
    unsigned short* Xb  = (unsigned short*)carve((size_t)npad * 128 * 2);  // bf16 layer input
    unsigned short* Hs  = (unsigned short*)carve((size_t)npad * 128 * 2);  // bf16 scaled GEMM out
    unsigned short* Hb  = (unsigned short*)carve((size_t)npad * 128 * 2);  // bf16 layer-1 result

    dim3 blk(256);
    int total = n * 128, total_pad = npad * 128;
    int nbin = (nE + BIN_TILE - 1) / BIN_TILE;

    // conversions (packw also zeroes gcur)
    packw_k<<<32768 / 256, blk, 0, stream>>>(W1, W2, Wp1, Wp2, gcur, nb);
    convx_k<<<(total_pad + 255) / 256, blk, 0, stream>>>(x, Xb, total, total_pad);

    // bucketed CSR build (replaces count/scan/scatter global-atomic pipeline)
    bin_k<<<nbin, blk, 0, stream>>>(src, dst, gcur, staging, nE, nb);
    bscan_k<<<1, dim3(512), 0, stream>>>(gcur, bbase, rowptr, n, nb, nE);
    build_k<<<nb, blk, 0, stream>>>(staging, bbase, rowptr, eidx, dinv, n);

    int nwave_blocks = (n + 3) / 4;

    // layer 1
    mfma_gemm_k<<<nblk64, blk, 0, stream>>>(Xb, Wp1, dinv, Hs, n);
    agg_ln_k<true><<<nwave_blocks, blk, 0, stream>>>(Hs, dinv, rowptr, eidx, b1, g1, be1, Hb, n);

    // layer 2 (Hb padding rows are finite garbage; OOB accum rows are discarded by store guard)
    mfma_gemm_k<<<nblk64, blk, 0, stream>>>(Hb, Wp2, dinv, Hs, n);
    agg_ln_k<false><<<nwave_blocks, blk, 0, stream>>>(Hs, dinv, rowptr, eidx, b2, g2, be2, out, n);
}

// Round 2
// 229.720 us; speedup vs baseline: 1.3386x; 1.0283x over previous
//
#include <hip/hip_runtime.h>

#define LN_EPS 1e-5f

typedef __attribute__((ext_vector_type(8))) short bf16x8;
typedef __attribute__((ext_vector_type(4))) float f32x4;

// Bucketed CSR build parameters: bucket = 128 consecutive dst nodes.
#define BSH 7
#define BSPAN 128
#define BCAP 4096   // staging capacity per bucket (mean 2048, std ~45 -> 45 sigma margin)
#define BIN_TILE 4096  // edges per bin_k block (16 per thread)

__device__ __forceinline__ unsigned short f2bf(float f) {
    union { float f; unsigned u; } x; x.f = f;
    unsigned r = (x.u + 0x7FFFu + ((x.u >> 16) & 1u)) >> 16;
    return (unsigned short)r;
}
__device__ __forceinline__ float bfbits2f(unsigned hi) {  // hi = bf16 bits already in [31:16]
    union { unsigned u; float f; } x; x.u = hi; return x.f;
}

// ---------- conversions / packing ----------
// X fp32 -> bf16, padded rows zeroed.
__global__ void convx_k(const float* __restrict__ X, unsigned short* __restrict__ Xb,
                        int total, int total_pad) {
    int i = blockIdx.x * blockDim.x + threadIdx.x;
    if (i < total_pad) Xb[i] = (i < total) ? f2bf(X[i]) : (unsigned short)0;
}

// Pack both W1 and W2 into B-fragment-contiguous bf16 layout:
// Wp[(((kc*128 + col)*4 + kb)*8) + j] = W[(kc*32 + kb*8 + j)*128 + col]
// Block 0 additionally zeroes gcur[0..nb).
__global__ void packw_k(const float* __restrict__ W1, const float* __restrict__ W2,
                        unsigned short* __restrict__ Wp1, unsigned short* __restrict__ Wp2,
                        int* __restrict__ gcur, int nb) {
    int idx = blockIdx.x * blockDim.x + threadIdx.x;  // 0..32767
    if (blockIdx.x == 0) {
        for (int i = threadIdx.x; i < nb; i += 256) gcur[i] = 0;
    }
    const float* W = (idx < 16384) ? W1 : W2;
    unsigned short* Wp = (idx < 16384) ? Wp1 : Wp2;
    int t = idx & 16383;
    int k = t >> 7, col = t & 127;
    int kc = k >> 5, kr = k & 31, kb = kr >> 3, j = kr & 7;
    Wp[(((kc * 128 + col) * 4 + kb) * 8) + j] = f2bf(W[k * 128 + col]);
}

// ---------- bucketed CSR build ----------
// Pass 1: counting-bin a tile of BIN_TILE edges into nb buckets via LDS counters;
// reserve a contiguous run per (block,bucket) with ONE global atomic per bucket;
// write packed entries (src | localdst<<17) as contiguous runs into bucket-major staging.
__global__ __launch_bounds__(256) void bin_k(const int* __restrict__ src,
                                             const int* __restrict__ dst,
                                             int* __restrict__ gcur,
                                             unsigned* __restrict__ staging,
                                             int nE, int nb) {
    __shared__ int cnt[512];
    __shared__ int gbase[512];
    int tid = threadIdx.x;
    for (int i = tid; i < nb; i += 256) cnt[i] = 0;
    __syncthreads();
    int e0 = blockIdx.x * BIN_TILE;
    unsigned pk[16];
    int bk[16];
    int rk[16];
#pragma unroll
    for (int i = 0; i < 16; ++i) {
        int e = e0 + i * 256 + tid;
        if (e < nE) {
            int s = src[e];
            int d = dst[e];
            int b = d >> BSH;
            rk[i] = atomicAdd(&cnt[b], 1);
            bk[i] = b;
            pk[i] = (unsigned)s | ((unsigned)(d & (BSPAN - 1)) << 17);
        } else {
            bk[i] = -1;
        }
    }
    __syncthreads();
    for (int i = tid; i < nb; i += 256) gbase[i] = atomicAdd(&gcur[i], cnt[i]);
    __syncthreads();
#pragma unroll
    for (int i = 0; i < 16; ++i) {
        if (bk[i] >= 0)
            staging[(size_t)bk[i] * BCAP + gbase[bk[i]] + rk[i]] = pk[i];
    }
}

// Tiny scan over bucket totals -> bucket base offsets; also writes rowptr[n].
__global__ __launch_bounds__(512) void bscan_k(const int* __restrict__ gcur,
                                               int* __restrict__ bbase,
                                               int* __restrict__ rowptr,
                                               int n, int nb, int nE) {
    __shared__ int s[512];
    int tid = threadIdx.x;
    int v = (tid < nb) ? gcur[tid] : 0;
    s[tid] = v;
    __syncthreads();
    for (int off = 1; off < 512; off <<= 1) {
        int t = (tid >= off) ? s[tid - off] : 0;
        __syncthreads();
        s[tid] += t;
        __syncthreads();
    }
    if (tid < nb) bbase[tid] = s[tid] - v;  // exclusive
    if (tid == nb - 1) { bbase[nb] = s[tid]; rowptr[n] = nE; }
}

// Pass 2: one block per bucket. Per-node counts + 128-wide scan + scatter,
// all in LDS. Produces rowptr, dinv, and the final dst-grouped eidx.
__global__ __launch_bounds__(256) void build_k(const unsigned* __restrict__ staging,
                                               const int* __restrict__ bbase,
                                               int* __restrict__ rowptr,
                                               int* __restrict__ eidx,
                                               float* __restrict__ dinv, int n) {
    __shared__ int cnt[BSPAN];
    __shared__ int off[BSPAN];
    __shared__ int s[BSPAN];
    int b = blockIdx.x;
    int tid = threadIdx.x;
    if (tid < BSPAN) cnt[tid] = 0;
    __syncthreads();
    int base = bbase[b];
    int total = bbase[b + 1] - base;
    const unsigned* stg = staging + (size_t)b * BCAP;
    unsigned ent[16];  // BCAP/256 = 16 max entries per thread; statically indexed
#pragma unroll
    for (int k = 0; k < 16; ++k) {
        int i = tid + k * 256;
        unsigned e = 0xFFFFFFFFu;  // sentinel: valid entries have bits[31:24]==0
        if (i < total) {
            e = stg[i];
            atomicAdd(&cnt[(e >> 17) & (BSPAN - 1)], 1);
        }
        ent[k] = e;
    }
    __syncthreads();
    // exclusive scan of cnt[0..127]
    if (tid < BSPAN) s[tid] = cnt[tid];
    __syncthreads();
    for (int o = 1; o < BSPAN; o <<= 1) {
        int t = (tid < BSPAN && tid >= o) ? s[tid - o] : 0;
        __syncthreads();
        if (tid < BSPAN) s[tid] += t;
        __syncthreads();
    }
    if (tid < BSPAN) {
        int excl = s[tid] - cnt[tid];
        off[tid] = excl;  // becomes the scatter cursor
        int node = b * BSPAN + tid;
        if (node < n) {
            rowptr[node] = base + excl;
            dinv[node] = rsqrtf((float)(cnt[tid] + 1));
        }
    }
    __syncthreads();
#pragma unroll
    for (int k = 0; k < 16; ++k) {
        unsigned e = ent[k];
        if (e != 0xFFFFFFFFu) {
            int ld = (e >> 17) & (BSPAN - 1);
            int p = atomicAdd(&off[ld], 1);
            eidx[base + p] = (int)(e & 0x1FFFFu);
        }
    }
}

// ---------- MFMA GEMM: Y[r,:] = bf16( dinv[r] * (Xb[r,:] @ W) ) ----------
// Block: 256 thr = 4 waves; block tile 64 rows x 128 cols.
// Wave (rgrp = wid&1, cgrp = wid>>1): 32 rows x 64 cols = 2 A-frags x 4 B-frags.
__global__ __launch_bounds__(256) void mfma_gemm_k(const unsigned short* __restrict__ Xb,
                                                   const unsigned short* __restrict__ Wp,
                                                   const float* __restrict__ dinv,
                                                   unsigned short* __restrict__ Y, int n) {
    int wid = threadIdx.x >> 6;
    int lane = threadIdx.x & 63;
    int rgrp = wid & 1;
    int cgrp = wid >> 1;
    int row0 = blockIdx.x * 64 + rgrp * 32;
    int m = lane & 15;
    int kb = lane >> 4;  // 0..3

    f32x4 acc[2][4] = {};
#pragma unroll
    for (int kc = 0; kc < 4; ++kc) {
        bf16x8 a[2], b[4];
#pragma unroll
        for (int rs = 0; rs < 2; ++rs) {
            int r = row0 + rs * 16 + m;
            a[rs] = *(const bf16x8*)(Xb + (size_t)r * 128 + kc * 32 + kb * 8);
        }
#pragma unroll
        for (int cf = 0; cf < 4; ++cf) {
            int col = cgrp * 64 + cf * 16 + m;
            b[cf] = *(const bf16x8*)(Wp + (((kc * 128 + col) * 4 + kb) * 8));
        }
#pragma unroll
        for (int rs = 0; rs < 2; ++rs)
#pragma unroll
            for (int cf = 0; cf < 4; ++cf)
                acc[rs][cf] = __builtin_amdgcn_mfma_f32_16x16x32_bf16(a[rs], b[cf], acc[rs][cf], 0, 0, 0);
    }
    // D layout: row = (lane>>4)*4 + reg, col = lane&15
#pragma unroll
    for (int rs = 0; rs < 2; ++rs) {
        int rbase = row0 + rs * 16 + kb * 4;
#pragma unroll
        for (int r = 0; r < 4; ++r) {
            int row = rbase + r;
            if (row >= n) continue;
            float dv = dinv[row];
#pragma unroll
            for (int cf = 0; cf < 4; ++cf) {
                int col = cgrp * 64 + cf * 16 + m;
                Y[(size_t)row * 128 + col] = f2bf(acc[rs][cf][r] * dv);
            }
        }
    }
}

// ---------- fused gather-aggregate + bias + LN + ReLU ----------
// One wave per node. Quarter-wave (16 lanes) per edge: lane q=lane&15 loads uint4
// (16B = 8 dims), so one load instruction gathers FOUR source rows (1 KB).
// Lane (q,g) accumulates dims 8q..8q+7 over its edge subset; quarter-groups are
// combined with shfl_xor(16/32); LN reduction runs over the 16-lane q axis.
#define ACCU(u) { \
    a0 += bfbits2f((u).x << 16); a1 += bfbits2f((u).x & 0xFFFF0000u); \
    a2 += bfbits2f((u).y << 16); a3 += bfbits2f((u).y & 0xFFFF0000u); \
    a4 += bfbits2f((u).z << 16); a5 += bfbits2f((u).z & 0xFFFF0000u); \
    a6 += bfbits2f((u).w << 16); a7 += bfbits2f((u).w & 0xFFFF0000u); }

template <bool OUT_BF16>
__global__ __launch_bounds__(256) void agg_ln_k(const unsigned short* __restrict__ Hs,
                                                const float* __restrict__ dinv,
                                                const int* __restrict__ rowptr,
                                                const int* __restrict__ eidx,
                                                const float* __restrict__ bias,
                                                const float* __restrict__ g,
                                                const float* __restrict__ beta,
                                                void* __restrict__ out, int n) {
    int wave = (blockIdx.x * blockDim.x + threadIdx.x) >> 6;
    int lane = threadIdx.x & 63;
    if (wave >= n) return;
    int q = lane & 15;
    int grp = lane >> 4;  // 0..3
    const uint4* H16 = (const uint4*)Hs;  // one uint4 = 8 bf16; row = 16 uint4

    float a0 = 0.f, a1 = 0.f, a2 = 0.f, a3 = 0.f, a4 = 0.f, a5 = 0.f, a6 = 0.f, a7 = 0.f;
    if (grp == 0) {
        uint4 sv = H16[(size_t)wave * 16 + q];
        ACCU(sv);
    }
    int beg = rowptr[wave];
    int end = rowptr[wave + 1];
    int eb = beg;
    // 8 edges per iteration: each quarter-group takes edges eb+grp and eb+4+grp.
    for (; eb + 7 < end; eb += 8) {
        int s0 = eidx[eb + grp];
        int s1 = eidx[eb + 4 + grp];
        uint4 u0 = H16[(size_t)s0 * 16 + q];
        uint4 u1 = H16[(size_t)s1 * 16 + q];
        ACCU(u0);
        ACCU(u1);
    }
    {   // tail: up to 7 edges
        int e0 = eb + grp;
        int e1 = eb + 4 + grp;
        if (e0 < end) { uint4 u = H16[(size_t)eidx[e0] * 16 + q]; ACCU(u); }
        if (e1 < end) { uint4 u = H16[(size_t)eidx[e1] * 16 + q]; ACCU(u); }
    }
    // combine the 4 quarter-groups (each held a disjoint edge subset)
    a0 += __shfl_xor(a0, 16); a1 += __shfl_xor(a1, 16);
    a2 += __shfl_xor(a2, 16); a3 += __shfl_xor(a3, 16);
    a4 += __shfl_xor(a4, 16); a5 += __shfl_xor(a5, 16);
    a6 += __shfl_xor(a6, 16); a7 += __shfl_xor(a7, 16);
    a0 += __shfl_xor(a0, 32); a1 += __shfl_xor(a1, 32);
    a2 += __shfl_xor(a2, 32); a3 += __shfl_xor(a3, 32);
    a4 += __shfl_xor(a4, 32); a5 += __shfl_xor(a5, 32);
    a6 += __shfl_xor(a6, 32); a7 += __shfl_xor(a7, 32);

    float dt = dinv[wave];
    float4 bi0 = ((const float4*)bias)[2 * q];
    float4 bi1 = ((const float4*)bias)[2 * q + 1];
    float v0 = a0 * dt + bi0.x, v1 = a1 * dt + bi0.y;
    float v2 = a2 * dt + bi0.z, v3 = a3 * dt + bi0.w;
    float v4 = a4 * dt + bi1.x, v5 = a5 * dt + bi1.y;
    float v6 = a6 * dt + bi1.z, v7 = a7 * dt + bi1.w;

    float sum = ((v0 + v1) + (v2 + v3)) + ((v4 + v5) + (v6 + v7));
    sum += __shfl_xor(sum, 1);
    sum += __shfl_xor(sum, 2);
    sum += __shfl_xor(sum, 4);
    sum += __shfl_xor(sum, 8);
    float mu = sum * (1.0f / 128.0f);
    float d0 = v0 - mu, d1 = v1 - mu, d2 = v2 - mu, d3 = v3 - mu;
    float d4 = v4 - mu, d5 = v5 - mu, d6 = v6 - mu, d7 = v7 - mu;
    float vs = ((d0 * d0 + d1 * d1) + (d2 * d2 + d3 * d3)) +
               ((d4 * d4 + d5 * d5) + (d6 * d6 + d7 * d7));
    vs += __shfl_xor(vs, 1);
    vs += __shfl_xor(vs, 2);
    vs += __shfl_xor(vs, 4);
    vs += __shfl_xor(vs, 8);
    float rstd = rsqrtf(vs * (1.0f / 128.0f) + LN_EPS);

    float4 gg0 = ((const float4*)g)[2 * q];
    float4 gg1 = ((const float4*)g)[2 * q + 1];
    float4 bb0 = ((const float4*)beta)[2 * q];
    float4 bb1 = ((const float4*)beta)[2 * q + 1];
    float o0 = fmaxf(d0 * rstd * gg0.x + bb0.x, 0.0f);
    float o1 = fmaxf(d1 * rstd * gg0.y + bb0.y, 0.0f);
    float o2 = fmaxf(d2 * rstd * gg0.z + bb0.z, 0.0f);
    float o3 = fmaxf(d3 * rstd * gg0.w + bb0.w, 0.0f);
    float o4 = fmaxf(d4 * rstd * gg1.x + bb1.x, 0.0f);
    float o5 = fmaxf(d5 * rstd * gg1.y + bb1.y, 0.0f);
    float o6 = fmaxf(d6 * rstd * gg1.z + bb1.z, 0.0f);
    float o7 = fmaxf(d7 * rstd * gg1.w + bb1.w, 0.0f);

    if (grp == 0) {  // 16 lanes cover the full row
        if (OUT_BF16) {
            uint4 pk;
            pk.x = (unsigned)f2bf(o0) | ((unsigned)f2bf(o1) << 16);
            pk.y = (unsigned)f2bf(o2) | ((unsigned)f2bf(o3) << 16);
            pk.z = (unsigned)f2bf(o4) | ((unsigned)f2bf(o5) << 16);
            pk.w = (unsigned)f2bf(o6) | ((unsigned)f2bf(o7) << 16);
            ((uint4*)out)[(size_t)wave * 16 + q] = pk;
        } else {
            float4* o = (float4*)out;
            o[(size_t)wave * 32 + 2 * q]     = make_float4(o0, o1, o2, o3);
            o[(size_t)wave * 32 + 2 * q + 1] = make_float4(o4, o5, o6, o7);
        }
    }
}

extern "C" void kernel_launch(void* const* d_in, const int* in_sizes, int n_in,
                              void* d_out, int out_size, void* d_ws, size_t ws_size,
                              hipStream_t stream) {
    const float* x   = (const float*)d_in[0];
    const int*   ei  = (const int*)d_in[1];
    const float* W1  = (const float*)d_in[2];
    const float* b1  = (const float*)d_in[3];
    const float* g1  = (const float*)d_in[4];
    const float* be1 = (const float*)d_in[5];
    const float* W2  = (const float*)d_in[6];
    const float* b2  = (const float*)d_in[7];
    const float* g2  = (const float*)d_in[8];
    const float* be2 = (const float*)d_in[9];
    float* out = (float*)d_out;

    int n  = in_sizes[0] / 128;   // 50000
    int nE = in_sizes[1] / 2;     // 800000
    const int* src = ei;
    const int* dst = ei + nE;

    int nb = (n + BSPAN - 1) >> BSH;  // 391 buckets
    int nblk64 = (n + 63) / 64;       // GEMM blocks
    int npad   = nblk64 * 64;         // padded rows for OOB-safe frag loads

    char* p = (char*)d_ws;
    auto carve = [&](size_t bytes) {
        char* r = p;
        p += (bytes + 255) & ~(size_t)255;
        return r;
    };
    float*    dinv    = (float*)carve((size_t)n * 4);
    int*      rowptr  = (int*)carve((size_t)(n + 1) * 4);
    int*      eidx    = (int*)carve((size_t)nE * 4);
    int*      gcur    = (int*)carve((size_t)nb * 4);
    int*      bbase   = (int*)carve((size_t)(nb + 1) * 4);
    unsigned* staging = (unsigned*)carve((size_t)nb * BCAP * 4);
    unsigned short* Wp1 = (unsigned short*)carve(16384 * 2);
    unsigned short* Wp2 = (unsigned short*)carve(16384 * 2);
    unsigned short* Xb  = (unsigned short*)carve((size_t)npad * 128 * 2);  // bf16 layer input
    unsigned short* Hs  = (unsigned short*)carve((size_t)npad * 128 * 2);  // bf16 scaled GEMM out
    unsigned short* Hb  = (unsigned short*)carve((size_t)npad * 128 * 2);  // bf16 layer-1 result

    dim3 blk(256);
    int total = n * 128, total_pad = npad * 128;
    int nbin = (nE + BIN_TILE - 1) / BIN_TILE;

    // conversions (packw also zeroes gcur)
    packw_k<<<32768 / 256, blk, 0, stream>>>(W1, W2, Wp1, Wp2, gcur, nb);
    convx_k<<<(total_pad + 255) / 256, blk, 0, stream>>>(x, Xb, total, total_pad);

    // bucketed CSR build
    bin_k<<<nbin, blk, 0, stream>>>(src, dst, gcur, staging, nE, nb);
    bscan_k<<<1, dim3(512), 0, stream>>>(gcur, bbase, rowptr, n, nb, nE);
    build_k<<<nb, blk, 0, stream>>>(staging, bbase, rowptr, eidx, dinv, n);

    int nwave_blocks = (n + 3) / 4;

    // layer 1
    mfma_gemm_k<<<nblk64, blk, 0, stream>>>(Xb, Wp1, dinv, Hs, n);
    agg_ln_k<true><<<nwave_blocks, blk, 0, stream>>>(Hs, dinv, rowptr, eidx, b1, g1, be1, Hb, n);

    // layer 2 (Hb padding rows are finite garbage; OOB accum rows are discarded by store guard)
    mfma_gemm_k<<<nblk64, blk, 0, stream>>>(Hb, Wp2, dinv, Hs, n);
    agg_ln_k<false><<<nwave_blocks, blk, 0, stream>>>(Hs, dinv, rowptr, eidx, b2, g2, be2, out, n);
}

// Round 3
// 218.212 us; speedup vs baseline: 1.4092x; 1.0527x over previous
//
#include <hip/hip_runtime.h>

#define LN_EPS 1e-5f

typedef __attribute__((ext_vector_type(8))) short bf16x8;
typedef __attribute__((ext_vector_type(4))) float f32x4;

// Bucketed CSR build parameters: bucket = 128 consecutive dst nodes.
#define BSH 7
#define BSPAN 128
#define BCAP 4096   // staging capacity per bucket (mean 2048, std ~45)
#define BIN_TILE 4096  // edges per bin_k block (16 per thread)

__device__ __forceinline__ unsigned short f2bf(float f) {
    union { float f; unsigned u; } x; x.f = f;
    unsigned r = (x.u + 0x7FFFu + ((x.u >> 16) & 1u)) >> 16;
    return (unsigned short)r;
}
__device__ __forceinline__ float bfbits2f(unsigned hi) {  // hi = bf16 bits already in [31:16]
    union { unsigned u; float f; } x; x.u = hi; return x.f;
}
// 2x f32 -> packed bf16 (RNE), gfx950 single instruction
__device__ __forceinline__ unsigned cvtpk_bf16(float lo, float hi) {
    unsigned r;
    asm("v_cvt_pk_bf16_f32 %0, %1, %2" : "=v"(r) : "v"(lo), "v"(hi));
    return r;
}

// ---------- W packing (+ gcur zeroing) ----------
// Wp[(((kc*128 + col)*4 + kb)*8) + j] = W[(kc*32 + kb*8 + j)*128 + col]
__global__ void packw_k(const float* __restrict__ W1, const float* __restrict__ W2,
                        unsigned short* __restrict__ Wp1, unsigned short* __restrict__ Wp2,
                        int* __restrict__ gcur, int nb) {
    int idx = blockIdx.x * blockDim.x + threadIdx.x;  // 0..32767
    if (blockIdx.x == 0) {
        for (int i = threadIdx.x; i < nb; i += 256) gcur[i] = 0;
    }
    const float* W = (idx < 16384) ? W1 : W2;
    unsigned short* Wp = (idx < 16384) ? Wp1 : Wp2;
    int t = idx & 16383;
    int k = t >> 7, col = t & 127;
    int kc = k >> 5, kr = k & 31, kb = kr >> 3, j = kr & 7;
    Wp[(((kc * 128 + col) * 4 + kb) * 8) + j] = f2bf(W[k * 128 + col]);
}

// ---------- bucketed CSR build ----------
// Pass 1: counting-bin BIN_TILE edges into nb buckets via LDS counters; reserve a
// contiguous run per (block,bucket) with one global atomic per bucket; write packed
// entries (src | localdst<<17) into bucket-major staging.
__global__ __launch_bounds__(256) void bin_k(const int* __restrict__ src,
                                             const int* __restrict__ dst,
                                             int* __restrict__ gcur,
                                             unsigned* __restrict__ staging,
                                             int nE, int nb) {
    __shared__ int cnt[512];
    __shared__ int gbase[512];
    int tid = threadIdx.x;
    for (int i = tid; i < nb; i += 256) cnt[i] = 0;
    __syncthreads();
    int e0 = blockIdx.x * BIN_TILE;
    unsigned pk[16];
    int bk[16];
    int rk[16];
#pragma unroll
    for (int i = 0; i < 16; ++i) {
        int e = e0 + i * 256 + tid;
        if (e < nE) {
            int s = src[e];
            int d = dst[e];
            int b = d >> BSH;
            rk[i] = atomicAdd(&cnt[b], 1);
            bk[i] = b;
            pk[i] = (unsigned)s | ((unsigned)(d & (BSPAN - 1)) << 17);
        } else {
            bk[i] = -1;
        }
    }
    __syncthreads();
    for (int i = tid; i < nb; i += 256) gbase[i] = atomicAdd(&gcur[i], cnt[i]);
    __syncthreads();
#pragma unroll
    for (int i = 0; i < 16; ++i) {
        if (bk[i] >= 0)
            staging[(size_t)bk[i] * BCAP + gbase[bk[i]] + rk[i]] = pk[i];
    }
}

// Pass 2: one block per bucket. Inline prefix over gcur (replaces bscan launch),
// then per-node counts + 128-wide scan + scatter, all in LDS.
// Produces rowptr, dinv, and the final dst-grouped eidx.
__global__ __launch_bounds__(256) void build_k(const unsigned* __restrict__ staging,
                                               const int* __restrict__ gcur,
                                               int* __restrict__ rowptr,
                                               int* __restrict__ eidx,
                                               float* __restrict__ dinv, int n, int nE) {
    __shared__ int cnt[BSPAN];
    __shared__ int off[BSPAN];
    __shared__ int s[BSPAN];
    __shared__ int red[4];
    int b = blockIdx.x;
    int tid = threadIdx.x;
    if (tid < BSPAN) cnt[tid] = 0;
    // base = sum gcur[0..b) via block reduction
    int part = 0;
    for (int i = tid; i < b; i += 256) part += gcur[i];
#pragma unroll
    for (int o = 32; o > 0; o >>= 1) part += __shfl_down(part, o);
    if ((tid & 63) == 0) red[tid >> 6] = part;
    __syncthreads();
    int base = red[0] + red[1] + red[2] + red[3];
    int total = gcur[b];
    if (b == 0 && tid == 0) rowptr[n] = nE;

    const unsigned* stg = staging + (size_t)b * BCAP;
    unsigned ent[16];  // BCAP/256 = 16 max entries per thread; statically indexed
#pragma unroll
    for (int k = 0; k < 16; ++k) {
        int i = tid + k * 256;
        unsigned e = 0xFFFFFFFFu;  // sentinel: valid entries have bits[31:24]==0
        if (i < total) {
            e = stg[i];
            atomicAdd(&cnt[(e >> 17) & (BSPAN - 1)], 1);
        }
        ent[k] = e;
    }
    __syncthreads();
    // exclusive scan of cnt[0..127]
    if (tid < BSPAN) s[tid] = cnt[tid];
    __syncthreads();
    for (int o = 1; o < BSPAN; o <<= 1) {
        int t = (tid < BSPAN && tid >= o) ? s[tid - o] : 0;
        __syncthreads();
        if (tid < BSPAN) s[tid] += t;
        __syncthreads();
    }
    if (tid < BSPAN) {
        int excl = s[tid] - cnt[tid];
        off[tid] = excl;  // becomes the scatter cursor
        int node = b * BSPAN + tid;
        if (node < n) {
            rowptr[node] = base + excl;
            dinv[node] = rsqrtf((float)(cnt[tid] + 1));
        }
    }
    __syncthreads();
#pragma unroll
    for (int k = 0; k < 16; ++k) {
        unsigned e = ent[k];
        if (e != 0xFFFFFFFFu) {
            int ld = (e >> 17) & (BSPAN - 1);
            int p = atomicAdd(&off[ld], 1);
            eidx[base + p] = (int)(e & 0x1FFFFu);
        }
    }
}

// ---------- MFMA GEMM: Y[r,:] = bf16( dinv[r] * (A[r,:] @ W) ) ----------
// Block: 256 thr = 4 waves; block tile 64 rows x 128 cols.
// Wave (rgrp = wid&1, cgrp = wid>>1): 32 rows x 64 cols = 2 A-frags x 4 B-frags.
// A_F32: A is fp32 (layer-1 input x), converted in-register via v_cvt_pk_bf16_f32.
template <bool A_F32>
__global__ __launch_bounds__(256) void mfma_gemm_k(const void* __restrict__ Ain,
                                                   const unsigned short* __restrict__ Wp,
                                                   const float* __restrict__ dinv,
                                                   unsigned short* __restrict__ Y, int n) {
    int wid = threadIdx.x >> 6;
    int lane = threadIdx.x & 63;
    int rgrp = wid & 1;
    int cgrp = wid >> 1;
    int row0 = blockIdx.x * 64 + rgrp * 32;
    int m = lane & 15;
    int kb = lane >> 4;  // 0..3

    f32x4 acc[2][4] = {};
#pragma unroll
    for (int kc = 0; kc < 4; ++kc) {
        bf16x8 a[2], b[4];
#pragma unroll
        for (int rs = 0; rs < 2; ++rs) {
            int r = row0 + rs * 16 + m;
            if (A_F32) {
                f32x4 f0 = {0.f, 0.f, 0.f, 0.f}, f1 = {0.f, 0.f, 0.f, 0.f};
                if (r < n) {
                    const float* ap = (const float*)Ain + (size_t)r * 128 + kc * 32 + kb * 8;
                    f0 = *(const f32x4*)ap;
                    f1 = *(const f32x4*)(ap + 4);
                }
                unsigned* w = (unsigned*)&a[rs];
                w[0] = cvtpk_bf16(f0.x, f0.y);
                w[1] = cvtpk_bf16(f0.z, f0.w);
                w[2] = cvtpk_bf16(f1.x, f1.y);
                w[3] = cvtpk_bf16(f1.z, f1.w);
            } else {
                a[rs] = *(const bf16x8*)((const unsigned short*)Ain + (size_t)r * 128 + kc * 32 + kb * 8);
            }
        }
#pragma unroll
        for (int cf = 0; cf < 4; ++cf) {
            int col = cgrp * 64 + cf * 16 + m;
            b[cf] = *(const bf16x8*)(Wp + (((kc * 128 + col) * 4 + kb) * 8));
        }
#pragma unroll
        for (int rs = 0; rs < 2; ++rs)
#pragma unroll
            for (int cf = 0; cf < 4; ++cf)
                acc[rs][cf] = __builtin_amdgcn_mfma_f32_16x16x32_bf16(a[rs], b[cf], acc[rs][cf], 0, 0, 0);
    }
    // D layout: row = (lane>>4)*4 + reg, col = lane&15
#pragma unroll
    for (int rs = 0; rs < 2; ++rs) {
        int rbase = row0 + rs * 16 + kb * 4;
#pragma unroll
        for (int r = 0; r < 4; ++r) {
            int row = rbase + r;
            if (row >= n) continue;
            float dv = dinv[row];
#pragma unroll
            for (int cf = 0; cf < 4; ++cf) {
                int col = cgrp * 64 + cf * 16 + m;
                Y[(size_t)row * 128 + col] = f2bf(acc[rs][cf][r] * dv);
            }
        }
    }
}

// ---------- fused gather-aggregate + bias + LN + ReLU ----------
// One wave per node. Quarter-wave (16 lanes) per edge: lane q loads uint4 (8 dims),
// one load instruction gathers FOUR source rows (1 KB). Fully predicated 8-edge
// iterations (no scalar tail): invalid lanes re-load the L1-resident self row and
// are masked out of the accumulate. Software-pipelined: next iteration's gathers
// are in flight during the current masked accumulate.
#define ACCU(u) { \
    a0 += bfbits2f((u).x << 16); a1 += bfbits2f((u).x & 0xFFFF0000u); \
    a2 += bfbits2f((u).y << 16); a3 += bfbits2f((u).y & 0xFFFF0000u); \
    a4 += bfbits2f((u).z << 16); a5 += bfbits2f((u).z & 0xFFFF0000u); \
    a6 += bfbits2f((u).w << 16); a7 += bfbits2f((u).w & 0xFFFF0000u); }

template <bool OUT_BF16>
__global__ __launch_bounds__(256) void agg_ln_k(const unsigned short* __restrict__ Hs,
                                                const float* __restrict__ dinv,
                                                const int* __restrict__ rowptr,
                                                const int* __restrict__ eidx,
                                                const float* __restrict__ bias,
                                                const float* __restrict__ g,
                                                const float* __restrict__ beta,
                                                void* __restrict__ out, int n) {
    int wave = (blockIdx.x * blockDim.x + threadIdx.x) >> 6;
    int lane = threadIdx.x & 63;
    if (wave >= n) return;
    int q = lane & 15;
    int grp = lane >> 4;  // 0..3
    const uint4* H16 = (const uint4*)Hs;  // one uint4 = 8 bf16; row = 16 uint4

    int beg = rowptr[wave];
    int end = rowptr[wave + 1];
    float dt = dinv[wave];

    float a0 = 0.f, a1 = 0.f, a2 = 0.f, a3 = 0.f, a4 = 0.f, a5 = 0.f, a6 = 0.f, a7 = 0.f;
    if (grp == 0) {  // self row (also warms L1 with the fallback row for masked lanes)
        uint4 sv = H16[(size_t)wave * 16 + q];
        ACCU(sv);
    }
    if (beg < end) {
        bool p0, p1;
        uint4 u0, u1;
        {
            int e0 = beg + grp, e1 = beg + 4 + grp;
            p0 = e0 < end; p1 = e1 < end;
            int i0 = wave, i1 = wave;
            if (p0) i0 = eidx[e0];
            if (p1) i1 = eidx[e1];
            u0 = H16[(size_t)i0 * 16 + q];
            u1 = H16[(size_t)i1 * 16 + q];
        }
        for (int eb = beg + 8;; eb += 8) {
            bool c0 = p0, c1 = p1;
            uint4 v0 = u0, v1 = u1;
            bool more = eb < end;  // wave-uniform
            if (more) {
                int e0 = eb + grp, e1 = eb + 4 + grp;
                p0 = e0 < end; p1 = e1 < end;
                int i0 = wave, i1 = wave;
                if (p0) i0 = eidx[e0];
                if (p1) i1 = eidx[e1];
                u0 = H16[(size_t)i0 * 16 + q];
                u1 = H16[(size_t)i1 * 16 + q];
            }
            if (c0) ACCU(v0);
            if (c1) ACCU(v1);
            if (!more) break;
        }
    }
    // combine the 4 quarter-groups (each held a disjoint edge subset)
    a0 += __shfl_xor(a0, 16); a1 += __shfl_xor(a1, 16);
    a2 += __shfl_xor(a2, 16); a3 += __shfl_xor(a3, 16);
    a4 += __shfl_xor(a4, 16); a5 += __shfl_xor(a5, 16);
    a6 += __shfl_xor(a6, 16); a7 += __shfl_xor(a7, 16);
    a0 += __shfl_xor(a0, 32); a1 += __shfl_xor(a1, 32);
    a2 += __shfl_xor(a2, 32); a3 += __shfl_xor(a3, 32);
    a4 += __shfl_xor(a4, 32); a5 += __shfl_xor(a5, 32);
    a6 += __shfl_xor(a6, 32); a7 += __shfl_xor(a7, 32);

    float4 bi0 = ((const float4*)bias)[2 * q];
    float4 bi1 = ((const float4*)bias)[2 * q + 1];
    float v0 = a0 * dt + bi0.x, v1 = a1 * dt + bi0.y;
    float v2 = a2 * dt + bi0.z, v3 = a3 * dt + bi0.w;
    float v4 = a4 * dt + bi1.x, v5 = a5 * dt + bi1.y;
    float v6 = a6 * dt + bi1.z, v7 = a7 * dt + bi1.w;

    float sum = ((v0 + v1) + (v2 + v3)) + ((v4 + v5) + (v6 + v7));
    sum += __shfl_xor(sum, 1);
    sum += __shfl_xor(sum, 2);
    sum += __shfl_xor(sum, 4);
    sum += __shfl_xor(sum, 8);
    float mu = sum * (1.0f / 128.0f);
    float d0 = v0 - mu, d1 = v1 - mu, d2 = v2 - mu, d3 = v3 - mu;
    float d4 = v4 - mu, d5 = v5 - mu, d6 = v6 - mu, d7 = v7 - mu;
    float vs = ((d0 * d0 + d1 * d1) + (d2 * d2 + d3 * d3)) +
               ((d4 * d4 + d5 * d5) + (d6 * d6 + d7 * d7));
    vs += __shfl_xor(vs, 1);
    vs += __shfl_xor(vs, 2);
    vs += __shfl_xor(vs, 4);
    vs += __shfl_xor(vs, 8);
    float rstd = rsqrtf(vs * (1.0f / 128.0f) + LN_EPS);

    float4 gg0 = ((const float4*)g)[2 * q];
    float4 gg1 = ((const float4*)g)[2 * q + 1];
    float4 bb0 = ((const float4*)beta)[2 * q];
    float4 bb1 = ((const float4*)beta)[2 * q + 1];
    float o0 = fmaxf(d0 * rstd * gg0.x + bb0.x, 0.0f);
    float o1 = fmaxf(d1 * rstd * gg0.y + bb0.y, 0.0f);
    float o2 = fmaxf(d2 * rstd * gg0.z + bb0.z, 0.0f);
    float o3 = fmaxf(d3 * rstd * gg0.w + bb0.w, 0.0f);
    float o4 = fmaxf(d4 * rstd * gg1.x + bb1.x, 0.0f);
    float o5 = fmaxf(d5 * rstd * gg1.y + bb1.y, 0.0f);
    float o6 = fmaxf(d6 * rstd * gg1.z + bb1.z, 0.0f);
    float o7 = fmaxf(d7 * rstd * gg1.w + bb1.w, 0.0f);

    if (grp == 0) {  // 16 lanes cover the full row
        if (OUT_BF16) {
            uint4 pk;
            pk.x = (unsigned)f2bf(o0) | ((unsigned)f2bf(o1) << 16);
            pk.y = (unsigned)f2bf(o2) | ((unsigned)f2bf(o3) << 16);
            pk.z = (unsigned)f2bf(o4) | ((unsigned)f2bf(o5) << 16);
            pk.w = (unsigned)f2bf(o6) | ((unsigned)f2bf(o7) << 16);
            ((uint4*)out)[(size_t)wave * 16 + q] = pk;
        } else {
            float4* o = (float4*)out;
            o[(size_t)wave * 32 + 2 * q]     = make_float4(o0, o1, o2, o3);
            o[(size_t)wave * 32 + 2 * q + 1] = make_float4(o4, o5, o6, o7);
        }
    }
}

extern "C" void kernel_launch(void* const* d_in, const int* in_sizes, int n_in,
                              void* d_out, int out_size, void* d_ws, size_t ws_size,
                              hipStream_t stream) {
    const float* x   = (const float*)d_in[0];
    const int*   ei  = (const int*)d_in[1];
    const float* W1  = (const float*)d_in[2];
    const float* b1  = (const float*)d_in[3];
    const float* g1  = (const float*)d_in[4];
    const float* be1 = (const float*)d_in[5];
    const float* W2  = (const float*)d_in[6];
    const float* b2  = (const float*)d_in[7];
    const float* g2  = (const float*)d_in[8];
    const float* be2 = (const float*)d_in[9];
    float* out = (float*)d_out;

    int n  = in_sizes[0] / 128;   // 50000
    int nE = in_sizes[1] / 2;     // 800000
    const int* src = ei;
    const int* dst = ei + nE;

    int nb = (n + BSPAN - 1) >> BSH;  // 391 buckets
    int nblk64 = (n + 63) / 64;       // GEMM blocks
    int npad   = nblk64 * 64;         // padded rows for OOB-safe frag loads

    char* p = (char*)d_ws;
    auto carve = [&](size_t bytes) {
        char* r = p;
        p += (bytes + 255) & ~(size_t)255;
        return r;
    };
    float*    dinv    = (float*)carve((size_t)n * 4);
    int*      rowptr  = (int*)carve((size_t)(n + 1) * 4);
    int*      eidx    = (int*)carve((size_t)nE * 4);
    int*      gcur    = (int*)carve((size_t)nb * 4);
    unsigned* staging = (unsigned*)carve((size_t)nb * BCAP * 4);
    unsigned short* Wp1 = (unsigned short*)carve(16384 * 2);
    unsigned short* Wp2 = (unsigned short*)carve(16384 * 2);
    unsigned short* Hs  = (unsigned short*)carve((size_t)npad * 128 * 2);  // bf16 scaled GEMM out
    unsigned short* Hb  = (unsigned short*)carve((size_t)npad * 128 * 2);  // bf16 layer-1 result

    dim3 blk(256);
    int nbin = (nE + BIN_TILE - 1) / BIN_TILE;
    int nwave_blocks = (n + 3) / 4;

    // prep: W packing + gcur zero
    packw_k<<<32768 / 256, blk, 0, stream>>>(W1, W2, Wp1, Wp2, gcur, nb);

    // bucketed CSR build (bscan folded into build_k)
    bin_k<<<nbin, blk, 0, stream>>>(src, dst, gcur, staging, nE, nb);
    build_k<<<nb, blk, 0, stream>>>(staging, gcur, rowptr, eidx, dinv, n, nE);

    // layer 1 (fp32 x converted in-register inside GEMM)
    mfma_gemm_k<true><<<nblk64, blk, 0, stream>>>(x, Wp1, dinv, Hs, n);
    agg_ln_k<true><<<nwave_blocks, blk, 0, stream>>>(Hs, dinv, rowptr, eidx, b1, g1, be1, Hb, n);

    // layer 2 (Hb padding rows are garbage; OOB accum rows are discarded by store guard)
    mfma_gemm_k<false><<<nblk64, blk, 0, stream>>>(Hb, Wp2, dinv, Hs, n);
    agg_ln_k<false><<<nwave_blocks, blk, 0, stream>>>(Hs, dinv, rowptr, eidx, b2, g2, be2, out, n);
}

// Round 5
// 211.174 us; speedup vs baseline: 1.4561x; 1.0333x over previous
//
#include <hip/hip_runtime.h>

#define LN_EPS 1e-5f

typedef __attribute__((ext_vector_type(8))) short bf16x8;
typedef __attribute__((ext_vector_type(4))) float f32x4;

// Bucketed CSR build parameters: bucket = 128 consecutive dst nodes.
#define BSH 7
#define BSPAN 128
#define BCAP 4096   // staging capacity per bucket (mean 2048, std ~45)
#define BIN_TILE 4096  // edges per bin_k block (16 per thread)

__device__ __forceinline__ unsigned short f2bf(float f) {
    union { float f; unsigned u; } x; x.f = f;
    unsigned r = (x.u + 0x7FFFu + ((x.u >> 16) & 1u)) >> 16;
    return (unsigned short)r;
}
__device__ __forceinline__ float bfbits2f(unsigned hi) {  // hi = bf16 bits already in [31:16]
    union { unsigned u; float f; } x; x.u = hi; return x.f;
}
// 2x f32 -> packed bf16 (RNE), gfx950 single instruction
__device__ __forceinline__ unsigned cvtpk_bf16(float lo, float hi) {
    unsigned r;
    asm("v_cvt_pk_bf16_f32 %0, %1, %2" : "=v"(r) : "v"(lo), "v"(hi));
    return r;
}

// ---------- W packing (+ gcur zeroing) ----------
// Wp[(((kc*128 + col)*4 + kb)*8) + j] = W[(kc*32 + kb*8 + j)*128 + col]
__global__ void packw_k(const float* __restrict__ W1, const float* __restrict__ W2,
                        unsigned short* __restrict__ Wp1, unsigned short* __restrict__ Wp2,
                        int* __restrict__ gcur, int nb) {
    int idx = blockIdx.x * blockDim.x + threadIdx.x;  // 0..32767
    if (blockIdx.x == 0) {
        for (int i = threadIdx.x; i < nb; i += 256) gcur[i] = 0;
    }
    const float* W = (idx < 16384) ? W1 : W2;
    unsigned short* Wp = (idx < 16384) ? Wp1 : Wp2;
    int t = idx & 16383;
    int k = t >> 7, col = t & 127;
    int kc = k >> 5, kr = k & 31, kb = kr >> 3, j = kr & 7;
    Wp[(((kc * 128 + col) * 4 + kb) * 8) + j] = f2bf(W[k * 128 + col]);
}

// ---------- bucketed CSR build ----------
// Pass 1: counting-bin BIN_TILE edges into nb buckets via LDS counters; reserve a
// contiguous run per (block,bucket) with one global atomic per bucket; write packed
// entries (src | localdst<<17) into bucket-major staging.
__global__ __launch_bounds__(256) void bin_k(const int* __restrict__ src,
                                             const int* __restrict__ dst,
                                             int* __restrict__ gcur,
                                             unsigned* __restrict__ staging,
                                             int nE, int nb) {
    __shared__ int cnt[512];
    __shared__ int gbase[512];
    int tid = threadIdx.x;
    for (int i = tid; i < nb; i += 256) cnt[i] = 0;
    __syncthreads();
    int e0 = blockIdx.x * BIN_TILE;
    unsigned pk[16];
    int bk[16];
    int rk[16];
#pragma unroll
    for (int i = 0; i < 16; ++i) {
        int e = e0 + i * 256 + tid;
        if (e < nE) {
            int s = src[e];
            int d = dst[e];
            int b = d >> BSH;
            rk[i] = atomicAdd(&cnt[b], 1);
            bk[i] = b;
            pk[i] = (unsigned)s | ((unsigned)(d & (BSPAN - 1)) << 17);
        } else {
            bk[i] = -1;
        }
    }
    __syncthreads();
    for (int i = tid; i < nb; i += 256) gbase[i] = atomicAdd(&gcur[i], cnt[i]);
    __syncthreads();
#pragma unroll
    for (int i = 0; i < 16; ++i) {
        if (bk[i] >= 0)
            staging[(size_t)bk[i] * BCAP + gbase[bk[i]] + rk[i]] = pk[i];
    }
}

// Pass 2: one block per bucket. Inline prefix over gcur (replaces bscan launch),
// then per-node counts + 128-wide scan + scatter, all in LDS.
// Produces rowptr, dinv, and the final dst-grouped eidx.
__global__ __launch_bounds__(256) void build_k(const unsigned* __restrict__ staging,
                                               const int* __restrict__ gcur,
                                               int* __restrict__ rowptr,
                                               int* __restrict__ eidx,
                                               float* __restrict__ dinv, int n, int nE) {
    __shared__ int cnt[BSPAN];
    __shared__ int off[BSPAN];
    __shared__ int s[BSPAN];
    __shared__ int red[4];
    int b = blockIdx.x;
    int tid = threadIdx.x;
    if (tid < BSPAN) cnt[tid] = 0;
    // base = sum gcur[0..b) via block reduction
    int part = 0;
    for (int i = tid; i < b; i += 256) part += gcur[i];
#pragma unroll
    for (int o = 32; o > 0; o >>= 1) part += __shfl_down(part, o);
    if ((tid & 63) == 0) red[tid >> 6] = part;
    __syncthreads();
    int base = red[0] + red[1] + red[2] + red[3];
    int total = gcur[b];
    if (b == 0 && tid == 0) rowptr[n] = nE;

    const unsigned* stg = staging + (size_t)b * BCAP;
    unsigned ent[16];  // BCAP/256 = 16 max entries per thread; statically indexed
#pragma unroll
    for (int k = 0; k < 16; ++k) {
        int i = tid + k * 256;
        unsigned e = 0xFFFFFFFFu;  // sentinel: valid entries have bits[31:24]==0
        if (i < total) {
            e = stg[i];
            atomicAdd(&cnt[(e >> 17) & (BSPAN - 1)], 1);
        }
        ent[k] = e;
    }
    __syncthreads();
    // exclusive scan of cnt[0..127]
    if (tid < BSPAN) s[tid] = cnt[tid];
    __syncthreads();
    for (int o = 1; o < BSPAN; o <<= 1) {
        int t = (tid < BSPAN && tid >= o) ? s[tid - o] : 0;
        __syncthreads();
        if (tid < BSPAN) s[tid] += t;
        __syncthreads();
    }
    if (tid < BSPAN) {
        int excl = s[tid] - cnt[tid];
        off[tid] = excl;  // becomes the scatter cursor
        int node = b * BSPAN + tid;
        if (node < n) {
            rowptr[node] = base + excl;
            dinv[node] = rsqrtf((float)(cnt[tid] + 1));
        }
    }
    __syncthreads();
#pragma unroll
    for (int k = 0; k < 16; ++k) {
        unsigned e = ent[k];
        if (e != 0xFFFFFFFFu) {
            int ld = (e >> 17) & (BSPAN - 1);
            int p = atomicAdd(&off[ld], 1);
            eidx[base + p] = (int)(e & 0x1FFFFu);
        }
    }
}

// ---------- MFMA GEMM: Y[r,:] = bf16( dinv[r] * (A[r,:] @ W) ) ----------
// Block: 256 thr = 4 waves; block tile 64 rows x 128 cols.
// Wave (rgrp = wid&1, cgrp = wid>>1): 32 rows x 64 cols = 2 A-frags x 4 B-frags.
// A_F32: A is fp32 (layer-1 input x), converted in-register via v_cvt_pk_bf16_f32.
template <bool A_F32>
__global__ __launch_bounds__(256) void mfma_gemm_k(const void* __restrict__ Ain,
                                                   const unsigned short* __restrict__ Wp,
                                                   const float* __restrict__ dinv,
                                                   unsigned short* __restrict__ Y, int n) {
    int wid = threadIdx.x >> 6;
    int lane = threadIdx.x & 63;
    int rgrp = wid & 1;
    int cgrp = wid >> 1;
    int row0 = blockIdx.x * 64 + rgrp * 32;
    int m = lane & 15;
    int kb = lane >> 4;  // 0..3

    f32x4 acc[2][4] = {};
#pragma unroll
    for (int kc = 0; kc < 4; ++kc) {
        bf16x8 a[2], b[4];
#pragma unroll
        for (int rs = 0; rs < 2; ++rs) {
            int r = row0 + rs * 16 + m;
            if (A_F32) {
                f32x4 f0 = {0.f, 0.f, 0.f, 0.f}, f1 = {0.f, 0.f, 0.f, 0.f};
                if (r < n) {
                    const float* ap = (const float*)Ain + (size_t)r * 128 + kc * 32 + kb * 8;
                    f0 = *(const f32x4*)ap;
                    f1 = *(const f32x4*)(ap + 4);
                }
                unsigned* w = (unsigned*)&a[rs];
                w[0] = cvtpk_bf16(f0.x, f0.y);
                w[1] = cvtpk_bf16(f0.z, f0.w);
                w[2] = cvtpk_bf16(f1.x, f1.y);
                w[3] = cvtpk_bf16(f1.z, f1.w);
            } else {
                a[rs] = *(const bf16x8*)((const unsigned short*)Ain + (size_t)r * 128 + kc * 32 + kb * 8);
            }
        }
#pragma unroll
        for (int cf = 0; cf < 4; ++cf) {
            int col = cgrp * 64 + cf * 16 + m;
            b[cf] = *(const bf16x8*)(Wp + (((kc * 128 + col) * 4 + kb) * 8));
        }
#pragma unroll
        for (int rs = 0; rs < 2; ++rs)
#pragma unroll
            for (int cf = 0; cf < 4; ++cf)
                acc[rs][cf] = __builtin_amdgcn_mfma_f32_16x16x32_bf16(a[rs], b[cf], acc[rs][cf], 0, 0, 0);
    }
    // D layout: row = (lane>>4)*4 + reg, col = lane&15
#pragma unroll
    for (int rs = 0; rs < 2; ++rs) {
        int rbase = row0 + rs * 16 + kb * 4;
#pragma unroll
        for (int r = 0; r < 4; ++r) {
            int row = rbase + r;
            if (row >= n) continue;
            float dv = dinv[row];
#pragma unroll
            for (int cf = 0; cf < 4; ++cf) {
                int col = cgrp * 64 + cf * 16 + m;
                Y[(size_t)row * 128 + col] = f2bf(acc[rs][cf][r] * dv);
            }
        }
    }
}

// ---------- fused gather-aggregate + bias + LN + ReLU ----------
// One wave per node. Quarter-wave (16 lanes) per edge-row (uint4 = 8 dims/lane).
// 16 edges per iteration (4 gather instructions), software-pipelined depth-2 ->
// 8 outstanding uint4 gathers per wave. Fully branchless: lanes past the degree
// gather the L1-hot self row and are nulled via a x0 scale in the FMA accumulate.
#define ACCS(u, s) { \
    a0 = fmaf(bfbits2f((u).x << 16), s, a0); a1 = fmaf(bfbits2f((u).x & 0xFFFF0000u), s, a1); \
    a2 = fmaf(bfbits2f((u).y << 16), s, a2); a3 = fmaf(bfbits2f((u).y & 0xFFFF0000u), s, a3); \
    a4 = fmaf(bfbits2f((u).z << 16), s, a4); a5 = fmaf(bfbits2f((u).z & 0xFFFF0000u), s, a5); \
    a6 = fmaf(bfbits2f((u).w << 16), s, a6); a7 = fmaf(bfbits2f((u).w & 0xFFFF0000u), s, a7); }

// Load edge-slot (EB+OFF+grp): predicated index select (self row when past end),
// unconditional gather, scale 1/0.
#define GSLOT(EB, OFF, U, S) { \
    int ee = (EB) + (OFF) + grp; \
    bool pp = ee < end; \
    int ec = pp ? ee : (end - 1); \
    int ix = eidx[ec]; \
    int ii = pp ? ix : wave; \
    U = H16[(size_t)ii * 16 + q]; \
    S = pp ? 1.0f : 0.0f; }

template <bool OUT_BF16>
__global__ __launch_bounds__(256) void agg_ln_k(const unsigned short* __restrict__ Hs,
                                                const float* __restrict__ dinv,
                                                const int* __restrict__ rowptr,
                                                const int* __restrict__ eidx,
                                                const float* __restrict__ bias,
                                                const float* __restrict__ g,
                                                const float* __restrict__ beta,
                                                void* __restrict__ out, int n) {
    int wave = (blockIdx.x * blockDim.x + threadIdx.x) >> 6;
    int lane = threadIdx.x & 63;
    if (wave >= n) return;
    int q = lane & 15;
    int grp = lane >> 4;  // 0..3
    const uint4* H16 = (const uint4*)Hs;  // one uint4 = 8 bf16; row = 16 uint4

    int beg = rowptr[wave];
    int end = rowptr[wave + 1];
    float dt = dinv[wave];

    float a0 = 0.f, a1 = 0.f, a2 = 0.f, a3 = 0.f, a4 = 0.f, a5 = 0.f, a6 = 0.f, a7 = 0.f;
    {   // self row (all 4 groups load it -> warms L1 fallback line; scale so only one counts)
        uint4 sv = H16[(size_t)wave * 16 + q];
        float ss = (grp == 0) ? 1.0f : 0.0f;
        ACCS(sv, ss);
    }
    if (beg < end) {
        uint4 c0, c1, c2, c3;
        float s0, s1, s2, s3;
        GSLOT(beg, 0, c0, s0);
        GSLOT(beg, 4, c1, s1);
        GSLOT(beg, 8, c2, s2);
        GSLOT(beg, 12, c3, s3);
        for (int eb = beg + 16;; eb += 16) {
            bool more = eb < end;  // wave-uniform
            uint4 n0 = c0, n1 = c0, n2 = c0, n3 = c0;
            float t0 = 0.f, t1 = 0.f, t2 = 0.f, t3 = 0.f;
            if (more) {
                GSLOT(eb, 0, n0, t0);
                GSLOT(eb, 4, n1, t1);
                GSLOT(eb, 8, n2, t2);
                GSLOT(eb, 12, n3, t3);
            }
            ACCS(c0, s0);
            ACCS(c1, s1);
            ACCS(c2, s2);
            ACCS(c3, s3);
            if (!more) break;
            c0 = n0; c1 = n1; c2 = n2; c3 = n3;
            s0 = t0; s1 = t1; s2 = t2; s3 = t3;
        }
    }
    // combine the 4 quarter-groups (each held a disjoint edge subset)
    a0 += __shfl_xor(a0, 16); a1 += __shfl_xor(a1, 16);
    a2 += __shfl_xor(a2, 16); a3 += __shfl_xor(a3, 16);
    a4 += __shfl_xor(a4, 16); a5 += __shfl_xor(a5, 16);
    a6 += __shfl_xor(a6, 16); a7 += __shfl_xor(a7, 16);
    a0 += __shfl_xor(a0, 32); a1 += __shfl_xor(a1, 32);
    a2 += __shfl_xor(a2, 32); a3 += __shfl_xor(a3, 32);
    a4 += __shfl_xor(a4, 32); a5 += __shfl_xor(a5, 32);
    a6 += __shfl_xor(a6, 32); a7 += __shfl_xor(a7, 32);

    float4 bi0 = ((const float4*)bias)[2 * q];
    float4 bi1 = ((const float4*)bias)[2 * q + 1];
    float v0 = a0 * dt + bi0.x, v1 = a1 * dt + bi0.y;
    float v2 = a2 * dt + bi0.z, v3 = a3 * dt + bi0.w;
    float v4 = a4 * dt + bi1.x, v5 = a5 * dt + bi1.y;
    float v6 = a6 * dt + bi1.z, v7 = a7 * dt + bi1.w;

    float sum = ((v0 + v1) + (v2 + v3)) + ((v4 + v5) + (v6 + v7));
    sum += __shfl_xor(sum, 1);
    sum += __shfl_xor(sum, 2);
    sum += __shfl_xor(sum, 4);
    sum += __shfl_xor(sum, 8);
    float mu = sum * (1.0f / 128.0f);
    float d0 = v0 - mu, d1 = v1 - mu, d2 = v2 - mu, d3 = v3 - mu;
    float d4 = v4 - mu, d5 = v5 - mu, d6 = v6 - mu, d7 = v7 - mu;
    float vs = ((d0 * d0 + d1 * d1) + (d2 * d2 + d3 * d3)) +
               ((d4 * d4 + d5 * d5) + (d6 * d6 + d7 * d7));
    vs += __shfl_xor(vs, 1);
    vs += __shfl_xor(vs, 2);
    vs += __shfl_xor(vs, 4);
    vs += __shfl_xor(vs, 8);
    float rstd = rsqrtf(vs * (1.0f / 128.0f) + LN_EPS);

    float4 gg0 = ((const float4*)g)[2 * q];
    float4 gg1 = ((const float4*)g)[2 * q + 1];
    float4 bb0 = ((const float4*)beta)[2 * q];
    float4 bb1 = ((const float4*)beta)[2 * q + 1];
    float o0 = fmaxf(d0 * rstd * gg0.x + bb0.x, 0.0f);
    float o1 = fmaxf(d1 * rstd * gg0.y + bb0.y, 0.0f);
    float o2 = fmaxf(d2 * rstd * gg0.z + bb0.z, 0.0f);
    float o3 = fmaxf(d3 * rstd * gg0.w + bb0.w, 0.0f);
    float o4 = fmaxf(d4 * rstd * gg1.x + bb1.x, 0.0f);
    float o5 = fmaxf(d5 * rstd * gg1.y + bb1.y, 0.0f);
    float o6 = fmaxf(d6 * rstd * gg1.z + bb1.z, 0.0f);
    float o7 = fmaxf(d7 * rstd * gg1.w + bb1.w, 0.0f);

    if (grp == 0) {  // 16 lanes cover the full row
        if (OUT_BF16) {
            uint4 pk;
            pk.x = (unsigned)f2bf(o0) | ((unsigned)f2bf(o1) << 16);
            pk.y = (unsigned)f2bf(o2) | ((unsigned)f2bf(o3) << 16);
            pk.z = (unsigned)f2bf(o4) | ((unsigned)f2bf(o5) << 16);
            pk.w = (unsigned)f2bf(o6) | ((unsigned)f2bf(o7) << 16);
            ((uint4*)out)[(size_t)wave * 16 + q] = pk;
        } else {
            float4* o = (float4*)out;
            o[(size_t)wave * 32 + 2 * q]     = make_float4(o0, o1, o2, o3);
            o[(size_t)wave * 32 + 2 * q + 1] = make_float4(o4, o5, o6, o7);
        }
    }
}

extern "C" void kernel_launch(void* const* d_in, const int* in_sizes, int n_in,
                              void* d_out, int out_size, void* d_ws, size_t ws_size,
                              hipStream_t stream) {
    const float* x   = (const float*)d_in[0];
    const int*   ei  = (const int*)d_in[1];
    const float* W1  = (const float*)d_in[2];
    const float* b1  = (const float*)d_in[3];
    const float* g1  = (const float*)d_in[4];
    const float* be1 = (const float*)d_in[5];
    const float* W2  = (const float*)d_in[6];
    const float* b2  = (const float*)d_in[7];
    const float* g2  = (const float*)d_in[8];
    const float* be2 = (const float*)d_in[9];
    float* out = (float*)d_out;

    int n  = in_sizes[0] / 128;   // 50000
    int nE = in_sizes[1] / 2;     // 800000
    const int* src = ei;
    const int* dst = ei + nE;

    int nb = (n + BSPAN - 1) >> BSH;  // 391 buckets
    int nblk64 = (n + 63) / 64;       // GEMM blocks
    int npad   = nblk64 * 64;         // padded rows for OOB-safe frag loads

    char* p = (char*)d_ws;
    auto carve = [&](size_t bytes) {
        char* r = p;
        p += (bytes + 255) & ~(size_t)255;
        return r;
    };
    float*    dinv    = (float*)carve((size_t)n * 4);
    int*      rowptr  = (int*)carve((size_t)(n + 1) * 4);
    int*      eidx    = (int*)carve((size_t)nE * 4);
    int*      gcur    = (int*)carve((size_t)nb * 4);
    unsigned* staging = (unsigned*)carve((size_t)nb * BCAP * 4);
    unsigned short* Wp1 = (unsigned short*)carve(16384 * 2);
    unsigned short* Wp2 = (unsigned short*)carve(16384 * 2);
    unsigned short* Hs  = (unsigned short*)carve((size_t)npad * 128 * 2);  // bf16 scaled GEMM out
    unsigned short* Hb  = (unsigned short*)carve((size_t)npad * 128 * 2);  // bf16 layer-1 result

    dim3 blk(256);
    int nbin = (nE + BIN_TILE - 1) / BIN_TILE;
    int nwave_blocks = (n + 3) / 4;

    // prep: W packing + gcur zero
    packw_k<<<32768 / 256, blk, 0, stream>>>(W1, W2, Wp1, Wp2, gcur, nb);

    // bucketed CSR build (bscan folded into build_k)
    bin_k<<<nbin, blk, 0, stream>>>(src, dst, gcur, staging, nE, nb);
    build_k<<<nb, blk, 0, stream>>>(staging, gcur, rowptr, eidx, dinv, n, nE);

    // layer 1 (fp32 x converted in-register inside GEMM)
    mfma_gemm_k<true><<<nblk64, blk, 0, stream>>>(x, Wp1, dinv, Hs, n);
    agg_ln_k<true><<<nwave_blocks, blk, 0, stream>>>(Hs, dinv, rowptr, eidx, b1, g1, be1, Hb, n);

    // layer 2 (Hb padding rows are garbage; OOB accum rows are discarded by store guard)
    mfma_gemm_k<false><<<nblk64, blk, 0, stream>>>(Hb, Wp2, dinv, Hs, n);
    agg_ln_k<false><<<nwave_blocks, blk, 0, stream>>>(Hs, dinv, rowptr, eidx, b2, g2, be2, out, n);
}